// Round 11
// baseline (224.669 us; speedup 1.0000x reference)
//
#include <hip/hip_runtime.h>
#include <hip/hip_fp16.h>

// CapsNet dynamic routing, B=256, P=2048, C=10, OUT=16, IN=8, 3 iters.
// R17: R16 + residency. R16's k_cap was latency-bound with every pipe low
// (VALU 30%, Mfma 3.6%, HBM 7%) at Occupancy 18% = 8 waves/CU: GRID=512 is
// exactly 2 four-wave blocks/CU. Fix WITHOUT adding traffic: TPB 512 = 2
// p-groups x 4 b-waves SHARING one 40KB W stage; each wave runs 8 p (half
// the serial chain), CU hosts 16 waves (2x R16). pg1's acc folds into pg0
// via LDS (stride 162 = 2 mod 32, conflict-free) before the coalesced part
// store -> part volume unchanged (21MB). launch_bounds(512,2): cap 256, no
// R12-style clamp; natural ~80 VGPR -> 2 blocks co-resident (83KB LDS ok).
// k_red: was 160 blocks = 0.6/CU, 128-long chains; now grid (160,4), each
// chunk sums 32 p-tiles, fp32 atomicAdd (4/cell, s memset once).
// k_prepu: block = p-pair so each 64B line of u is fully consumed (exact
// 16.8MB fetch), writes stay 4KB-contiguous per wave.
// MFMA mapping (R15/R16, verified): A = W[p][c][o=col][0..8) (original
// layout, 16B/lane), B = uT row (quad0; quads1-3 zero = K-pad), C/D
// lane(quad,col) = uh[o=quad*4+reg][b=col]. Softmax: 2 shfl_xor per c, then
// all-10 in-lane. lg deleted via b3 = uhat.(v1+v2) algebra (R16).
// Passes: cap<0>: part=sum_p uhat -> red -> s1; cap<1>: v1=squash(.1 s1),
// part=sum softmax(uhat.v1)*uhat -> red -> s2; cap<2>: v12=v1+squash(s2),
// part -> red -> s3; k_out: squash(s3).

#define Bn 256
#define Pn 2048
#define Cn 10
#define On 16
#define In 8
#define ROW 160
#define BT 64
#define PPB 16
#define NPT (Pn / PPB)         // 128
#define TPB 512
#define GRID ((Bn / BT) * NPT) // 512 blocks of 512 -> 2 blocks/CU, 16 waves

typedef _Float16 f16x8 __attribute__((ext_vector_type(8)));
typedef _Float16 h2f __attribute__((ext_vector_type(2)));
typedef float f32x4 __attribute__((ext_vector_type(4)));

__device__ __forceinline__ void gl_lds16(const void* g, void* l) {
  __builtin_amdgcn_global_load_lds(
      (const __attribute__((address_space(1))) unsigned int*)g,
      (__attribute__((address_space(3))) unsigned int*)l, 16, 0, 0);
}

__device__ __forceinline__ h2f pack2(float a, float b) {
  __half2 t = __floats2half2_rn(a, b);
  return *reinterpret_cast<h2f*>(&t);
}

// ---- one-time W cast (layout unchanged) ----
__global__ __launch_bounds__(256) void k_prepw(const float* __restrict__ W,
                                               _Float16* __restrict__ Wh) {
  const size_t base = (size_t)blockIdx.x * 1280;
#pragma unroll
  for (int r = 0; r < 5; ++r) {
    const int i = threadIdx.x + 256 * r;
    Wh[base + i] = (_Float16)W[base + i];
  }
}

// ---- one-time u transpose+cast: block = p-pair, thread = b.
// Lane reads its full 64B line (both p's) -> exact-line fetch; writes are
// 16B/lane consecutive -> 4KB contiguous per wave store.
__global__ __launch_bounds__(256) void k_prepu(const float* __restrict__ u,
                                               _Float16* __restrict__ uT) {
  const int p2 = blockIdx.x * 2;
  const int b = threadIdx.x;
  const float4* src = reinterpret_cast<const float4*>(u + ((size_t)b * Pn + p2) * In);
  const float4 q0 = src[0], q1 = src[1], q2 = src[2], q3 = src[3];
  f16x8 o0, o1;
  o0[0] = (_Float16)q0.x; o0[1] = (_Float16)q0.y; o0[2] = (_Float16)q0.z; o0[3] = (_Float16)q0.w;
  o0[4] = (_Float16)q1.x; o0[5] = (_Float16)q1.y; o0[6] = (_Float16)q1.z; o0[7] = (_Float16)q1.w;
  o1[0] = (_Float16)q2.x; o1[1] = (_Float16)q2.y; o1[2] = (_Float16)q2.z; o1[3] = (_Float16)q2.w;
  o1[4] = (_Float16)q3.x; o1[5] = (_Float16)q3.y; o1[6] = (_Float16)q3.z; o1[7] = (_Float16)q3.w;
  *reinterpret_cast<f16x8*>(uT + ((size_t)p2 * Bn + b) * In) = o0;
  *reinterpret_cast<f16x8*>(uT + ((size_t)(p2 + 1) * Bn + b) * In) = o1;
}

template <int MODE>
__global__ __launch_bounds__(TPB, 2) void k_cap(const _Float16* __restrict__ uT,
                                                const _Float16* __restrict__ Wh,
                                                const float* __restrict__ s1,
                                                const float* __restrict__ s2,
                                                float* __restrict__ part) {
  // arena: wH fp16 (16p x 2560B = 40960B) / tail sAcc[64][162] (41448B)
  __shared__ float arena[10368]; // 41472 B
  _Float16* wH = reinterpret_cast<_Float16*>(arena);
  const int x = blockIdx.x;
  const int bt = x >> 7;   // 4 b-tiles
  const int pt = x & 127;  // 128 p-tiles
  const int tid = threadIdx.x;
  const int w = tid >> 6;
  const int pg = w >> 2;      // p-group: waves 0-3 -> p 0..8, 4-7 -> p 8..16
  const int wq = w & 3;       // b-subtile wave
  const int lane = tid & 63;
  const int col = lane & 15;  // b within wave tile; also A's o-row
  const int quad = lane >> 4; // o-quad in C/D; k-group (only quad0 real)
  const int b = bt * BT + wq * 16 + col;
  const int p0 = pt * PPB;

  // ---- stage W (original layout, linear) via async DMA: 5 x 16B rounds
  {
    const char* src = reinterpret_cast<const char*>(Wh + (size_t)p0 * 1280);
    char* dst = reinterpret_cast<char*>(wH);
#pragma unroll
    for (int r = 0; r < 5; ++r)
      gl_lds16(src + r * 8192 + tid * 16, dst + r * 8192 + tid * 16);
  }

  // ---- v packed h2 (MODE1: v1; MODE2: v1+v2), overlaps DMA ----
  h2f vh[Cn][2];
  if (MODE >= 1) {
    const float4* spA = reinterpret_cast<const float4*>(s1 + (size_t)b * ROW);
    const float4* spB = reinterpret_cast<const float4*>(s2 + (size_t)b * ROW);
#pragma unroll
    for (int c = 0; c < Cn; ++c) {
      const float4 a0 = spA[c * 4 + 0], a1 = spA[c * 4 + 1];
      const float4 a2 = spA[c * 4 + 2], a3 = spA[c * 4 + 3];
      float sqA = a0.x * a0.x + a0.y * a0.y + a0.z * a0.z + a0.w * a0.w;
      sqA += a1.x * a1.x + a1.y * a1.y + a1.z * a1.z + a1.w * a1.w;
      sqA += a2.x * a2.x + a2.y * a2.y + a2.z * a2.z + a2.w * a2.w;
      sqA += a3.x * a3.x + a3.y * a3.y + a3.z * a3.z + a3.w * a3.w;
      sqA *= 0.01f; // v1 scale is always 0.1
      const float facA = 0.1f * (sqA / (1.f + sqA)) / sqrtf(sqA + 1e-9f);
      const float4 qa = spA[c * 4 + quad]; // L1 re-hit
      float v0 = facA * qa.x, v1_ = facA * qa.y;
      float v2_ = facA * qa.z, v3_ = facA * qa.w;
      if (MODE == 2) { // add v2 = squash(s2)
        const float4 b0 = spB[c * 4 + 0], b1 = spB[c * 4 + 1];
        const float4 b2 = spB[c * 4 + 2], b3 = spB[c * 4 + 3];
        float sqB = b0.x * b0.x + b0.y * b0.y + b0.z * b0.z + b0.w * b0.w;
        sqB += b1.x * b1.x + b1.y * b1.y + b1.z * b1.z + b1.w * b1.w;
        sqB += b2.x * b2.x + b2.y * b2.y + b2.z * b2.z + b2.w * b2.w;
        sqB += b3.x * b3.x + b3.y * b3.y + b3.z * b3.z + b3.w * b3.w;
        const float facB = (sqB / (1.f + sqB)) / sqrtf(sqB + 1e-9f);
        const float4 qb = spB[c * 4 + quad];
        v0 += facB * qb.x; v1_ += facB * qb.y;
        v2_ += facB * qb.z; v3_ += facB * qb.w;
      }
      vh[c][0] = pack2(v0, v1_);
      vh[c][1] = pack2(v2_, v3_);
    }
  }

  f32x4 acc[Cn];
  const f32x4 zc = {0.f, 0.f, 0.f, 0.f};
#pragma unroll
  for (int c = 0; c < Cn; ++c) acc[c] = zc;

  const _Float16* urow = uT + ((size_t)(p0 + pg * 8) * Bn + b) * In;
  f16x8 uf = *reinterpret_cast<const f16x8*>(urow);
  const f16x8 zb = {0, 0, 0, 0, 0, 0, 0, 0};
  const bool isq0 = (quad == 0);

  __syncthreads(); // drains DMA -> wH ready

  for (int ip = 0; ip < 8; ++ip) {
    f16x8 ufn = uf;
    if (ip + 1 < 8) // u prefetch (named reg); 256B/wave contiguous
      ufn = *reinterpret_cast<const f16x8*>(urow + (size_t)(ip + 1) * Bn * In);
    const f16x8 ub = isq0 ? uf : zb; // quads 1-3: K-pad zeros
    const _Float16* wp = wH + (pg * 8 + ip) * 1280 + col * 8; // A: W[p][c][col]

    if (MODE == 0) {
#pragma unroll
      for (int c = 0; c < Cn; ++c) {
        const f16x8 aW = *reinterpret_cast<const f16x8*>(wp + c * 128);
        acc[c] = __builtin_amdgcn_mfma_f32_16x16x32_f16(aW, ub, acc[c], 0, 0, 0);
      }
    } else {
      float lf[Cn];
      h2f uhh[Cn][2];
#pragma unroll
      for (int c = 0; c < Cn; ++c) {
        const f16x8 aW = *reinterpret_cast<const f16x8*>(wp + c * 128);
        const f32x4 uh =
            __builtin_amdgcn_mfma_f32_16x16x32_f16(aW, ub, zc, 0, 0, 0);
        float lp = uh[0] * (float)vh[c][0][0];
        lp = __builtin_fmaf(uh[1], (float)vh[c][0][1], lp);
        lp = __builtin_fmaf(uh[2], (float)vh[c][1][0], lp);
        lp = __builtin_fmaf(uh[3], (float)vh[c][1][1], lp);
        lf[c] = lp;
        uhh[c][0] = pack2(uh[0], uh[1]); // packed: 20 regs not 40
        uhh[c][1] = pack2(uh[2], uh[3]);
      }
      // reduce over 4 o-quads: 2 shuffles per c (b stays in-lane)
#pragma unroll
      for (int c = 0; c < Cn; ++c) {
        lf[c] += __shfl_xor(lf[c], 16, 64);
        lf[c] += __shfl_xor(lf[c], 32, 64);
      }
      // softmax over 10 in-lane (max3 tree shortens the serial chain)
      float m = fmaxf(fmaxf(__builtin_fmaf(0.f, 0.f, lf[0]), lf[1]), lf[2]);
      m = fmaxf(m, fmaxf(fmaxf(lf[3], lf[4]), fmaxf(lf[5], lf[6])));
      m = fmaxf(m, fmaxf(fmaxf(lf[7], lf[8]), lf[9]));
      float ss = 0.f;
#pragma unroll
      for (int c = 0; c < Cn; ++c) {
        lf[c] = __expf(lf[c] - m);
        ss += lf[c];
      }
      const float inv = 1.f / ss;
#pragma unroll
      for (int c = 0; c < Cn; ++c) {
        const float cv = lf[c] * inv;
        acc[c][0] = __builtin_fmaf(cv, (float)uhh[c][0][0], acc[c][0]);
        acc[c][1] = __builtin_fmaf(cv, (float)uhh[c][0][1], acc[c][1]);
        acc[c][2] = __builtin_fmaf(cv, (float)uhh[c][1][0], acc[c][2]);
        acc[c][3] = __builtin_fmaf(cv, (float)uhh[c][1][1], acc[c][3]);
      }
    }
    uf = ufn;
  }

  // ---- tail: pg1 -> LDS (stride 162 = 2 mod 32, conflict-free), pg0 adds
  // and stores part coalesced. Volume unchanged vs R16 (21MB, no atomics).
  __syncthreads(); // all wH reads done before arena reuse
  float* sAcc = arena;
  const int row = wq * 16 + col;
  if (pg == 1) {
    float* dst = &sAcc[row * 162 + quad * 4];
#pragma unroll
    for (int c = 0; c < Cn; ++c)
      *reinterpret_cast<f32x4*>(dst + c * 16) = acc[c];
  }
  __syncthreads();
  if (pg == 0) {
    const float* srcp = &sAcc[row * 162 + quad * 4];
    float* pb = part + ((size_t)x * BT + row) * ROW;
#pragma unroll
    for (int c = 0; c < Cn; ++c) {
      f32x4 t = *reinterpret_cast<const f32x4*>(srcp + c * 16);
      t = t + acc[c];
      *reinterpret_cast<f32x4*>(pb + c * 16 + quad * 4) = t;
    }
  }
}

// ---- sum partials -> s. grid (160, 4): chunk = 32 p-tiles; 4 atomic
// contenders per cell (s pre-zeroed once). Coalesced reads per wave.
__global__ __launch_bounds__(256) void k_red(const float* __restrict__ part,
                                             float* __restrict__ s) {
  const int cell = blockIdx.x * 256 + threadIdx.x; // [0, 40960)
  const int chunk = blockIdx.y;                    // 0..3
  const int b = cell / 160, rem = cell - 160 * b;
  const int bt = b >> 6, bl = b & 63;
  const float* p0 =
      part + ((size_t)(bt * NPT + chunk * 32) * BT + bl) * ROW + rem;
  float a0 = 0.f, a1 = 0.f, a2 = 0.f, a3 = 0.f;
  float a4 = 0.f, a5 = 0.f, a6 = 0.f, a7 = 0.f;
#pragma unroll
  for (int pt = 0; pt < 32; pt += 8) { // 8 independent load chains
    a0 += p0[(size_t)(pt + 0) * BT * ROW];
    a1 += p0[(size_t)(pt + 1) * BT * ROW];
    a2 += p0[(size_t)(pt + 2) * BT * ROW];
    a3 += p0[(size_t)(pt + 3) * BT * ROW];
    a4 += p0[(size_t)(pt + 4) * BT * ROW];
    a5 += p0[(size_t)(pt + 5) * BT * ROW];
    a6 += p0[(size_t)(pt + 6) * BT * ROW];
    a7 += p0[(size_t)(pt + 7) * BT * ROW];
  }
  atomicAdd(&s[cell], ((a0 + a1) + (a2 + a3)) + ((a4 + a5) + (a6 + a7)));
}

__global__ __launch_bounds__(256) void k_out(const float* __restrict__ s,
                                             float* __restrict__ out) {
  const int gi = blockIdx.x * 256 + threadIdx.x; // [0, 2560) = (b,c)
  const int b = gi / 10, c = gi - 10 * b;
  const float* sp = s + (size_t)b * ROW + c * 16;
  float sq = 0.f;
#pragma unroll
  for (int o = 0; o < On; ++o) { const float xx = sp[o]; sq += xx * xx; }
  const float fac = (sq / (1.f + sq)) / sqrtf(sq + 1e-9f);
  float* op = out + (size_t)b * ROW + c * 16;
#pragma unroll
  for (int o = 0; o < On; ++o) op[o] = fac * sp[o];
}

extern "C" void kernel_launch(void* const* d_in, const int* in_sizes, int n_in,
                              void* d_out, int out_size, void* d_ws, size_t ws_size,
                              hipStream_t stream) {
  (void)in_sizes; (void)n_in; (void)out_size;
  const float* u = (const float*)d_in[0];
  const float* W = (const float*)d_in[1];
  float* out = (float*)d_out;
  float* s1 = (float*)d_ws;                    // 3 x [256][160] fp32
  float* s2 = s1 + (size_t)Bn * ROW;
  float* s3 = s2 + (size_t)Bn * ROW;
  float* part = s3 + (size_t)Bn * ROW;         // [512][64][160] fp32, 21MB
  _Float16* Wh = (_Float16*)(part + (size_t)GRID * BT * ROW); // 5.25MB
  _Float16* uTp = Wh + (size_t)Pn * Cn * On * In;             // 8.4MB
  const size_t need =
      ((size_t)3 * Bn * ROW + (size_t)GRID * BT * ROW) * sizeof(float) +
      ((size_t)Pn * Cn * On * In + (size_t)Pn * Bn * In) * sizeof(_Float16);
  if (ws_size < need) return;
  hipMemsetAsync(s1, 0, (size_t)3 * Bn * ROW * sizeof(float), stream);
  k_prepw<<<Pn, 256, 0, stream>>>(W, Wh);
  k_prepu<<<Pn / 2, 256, 0, stream>>>(u, uTp);
  k_cap<0><<<GRID, TPB, 0, stream>>>(uTp, Wh, s1, s1, part);
  k_red<<<dim3(160, 4), 256, 0, stream>>>(part, s1);
  k_cap<1><<<GRID, TPB, 0, stream>>>(uTp, Wh, s1, s1, part);
  k_red<<<dim3(160, 4), 256, 0, stream>>>(part, s2);
  k_cap<2><<<GRID, TPB, 0, stream>>>(uTp, Wh, s1, s2, part);
  k_red<<<dim3(160, 4), 256, 0, stream>>>(part, s3);
  k_out<<<10, 256, 0, stream>>>(s3, out);
}

// Round 12
// 184.388 us; speedup vs baseline: 1.2185x; 1.2185x over previous
//
#include <hip/hip_runtime.h>
#include <hip/hip_fp16.h>

// CapsNet dynamic routing, B=256, P=2048, C=10, OUT=16, IN=8, 3 iters.
// R18 = R16 + in-thread 2-p ILP. Occupancy is empirically pinned at ~8
// waves/CU across ALL configs (R11-R17; R17's (512,2) even halved blocks/CU
// to 1 - the 2nd launch_bounds arg is waves/EU: k = w*4/(B/64)). So the
// per-p serial chain (ds_read -> MFMA -> logit fma -> 2 shuffles -> max tree
// -> 10 exp -> sum -> rcp -> acc, ~600cyc, walked 16x per wave) must be
// overlapped with ILP, not TLP: process p and p+1 per iteration, fully
// independent chains, statically unrolled with named A/B values (rule-#20
// clean). VGPR ~76 -> ~140-150, under the (256,2) cap of 256 -> no spill
// (verify: FETCH stays ~8MB).
// Also: k_red split (160,4) w/ 32-tile chunks + atomicAdd into memset s
// (was 0.6 blocks/CU, 128-long chains); k_prepu paired (exact-line fetch).
// Carried from R16: NO atomics in k_cap (owner-unique coalesced part
// stores), lg DELETED via b3 = uhat.(v1+v2), uT[p][b][8] fp16, MFMA mapping
// A = W[p][c][o=col][0..8) (original layout, 16B/lane), B = uT row (quad0;
// quads1-3 zero = K-pad), C/D lane(quad,col) = uh[o=quad*4+reg][b=col],
// softmax 2 shfl_xor per c then all-10 in-lane, one barrier per kernel.
// Passes: cap<0>: part=sum_p uhat -> red -> s1; cap<1>: v1=squash(.1 s1),
// part=sum softmax(uhat.v1)*uhat -> red -> s2; cap<2>: v12=v1+squash(s2),
// part -> red -> s3; k_out: squash(s3).

#define Bn 256
#define Pn 2048
#define Cn 10
#define On 16
#define In 8
#define ROW 160
#define BT 64
#define PPB 16
#define NPT (Pn / PPB)         // 128
#define TPB 256
#define GRID ((Bn / BT) * NPT) // 512

typedef _Float16 f16x8 __attribute__((ext_vector_type(8)));
typedef _Float16 h2f __attribute__((ext_vector_type(2)));
typedef float f32x4 __attribute__((ext_vector_type(4)));

__device__ __forceinline__ void gl_lds16(const void* g, void* l) {
  __builtin_amdgcn_global_load_lds(
      (const __attribute__((address_space(1))) unsigned int*)g,
      (__attribute__((address_space(3))) unsigned int*)l, 16, 0, 0);
}

__device__ __forceinline__ h2f pack2(float a, float b) {
  __half2 t = __floats2half2_rn(a, b);
  return *reinterpret_cast<h2f*>(&t);
}

// ---- one-time W cast (layout unchanged) ----
__global__ __launch_bounds__(256) void k_prepw(const float* __restrict__ W,
                                               _Float16* __restrict__ Wh) {
  const size_t base = (size_t)blockIdx.x * 1280;
#pragma unroll
  for (int r = 0; r < 5; ++r) {
    const int i = threadIdx.x + 256 * r;
    Wh[base + i] = (_Float16)W[base + i];
  }
}

// ---- one-time u transpose+cast: block = p-pair, thread = b (exact-line) ----
__global__ __launch_bounds__(256) void k_prepu(const float* __restrict__ u,
                                               _Float16* __restrict__ uT) {
  const int p2 = blockIdx.x * 2;
  const int b = threadIdx.x;
  const float4* src = reinterpret_cast<const float4*>(u + ((size_t)b * Pn + p2) * In);
  const float4 q0 = src[0], q1 = src[1], q2 = src[2], q3 = src[3];
  f16x8 o0, o1;
  o0[0] = (_Float16)q0.x; o0[1] = (_Float16)q0.y; o0[2] = (_Float16)q0.z; o0[3] = (_Float16)q0.w;
  o0[4] = (_Float16)q1.x; o0[5] = (_Float16)q1.y; o0[6] = (_Float16)q1.z; o0[7] = (_Float16)q1.w;
  o1[0] = (_Float16)q2.x; o1[1] = (_Float16)q2.y; o1[2] = (_Float16)q2.z; o1[3] = (_Float16)q2.w;
  o1[4] = (_Float16)q3.x; o1[5] = (_Float16)q3.y; o1[6] = (_Float16)q3.z; o1[7] = (_Float16)q3.w;
  *reinterpret_cast<f16x8*>(uT + ((size_t)p2 * Bn + b) * In) = o0;
  *reinterpret_cast<f16x8*>(uT + ((size_t)(p2 + 1) * Bn + b) * In) = o1;
}

template <int MODE>
__global__ __launch_bounds__(TPB, 2) void k_cap(const _Float16* __restrict__ uT,
                                                const _Float16* __restrict__ Wh,
                                                const float* __restrict__ s1,
                                                const float* __restrict__ s2,
                                                float* __restrict__ part) {
  __shared__ _Float16 wH[PPB * 1280]; // 40960 B, staged once
  const int x = blockIdx.x;
  const int bt = x >> 7;   // 4 b-tiles
  const int pt = x & 127;  // 128 p-tiles
  const int tid = threadIdx.x;
  const int w = tid >> 6;
  const int lane = tid & 63;
  const int col = lane & 15;  // b within wave tile; also A's o-row
  const int quad = lane >> 4; // o-quad in C/D; k-group (only quad0 real)
  const int b = bt * BT + w * 16 + col;
  const int p0 = pt * PPB;

  // ---- stage W (original layout, linear) via async DMA: 10 x 16B rounds
  {
    const char* src = reinterpret_cast<const char*>(Wh + (size_t)p0 * 1280);
    char* dst = reinterpret_cast<char*>(wH);
#pragma unroll
    for (int r = 0; r < 10; ++r)
      gl_lds16(src + r * 4096 + tid * 16, dst + r * 4096 + tid * 16);
  }

  // ---- v packed h2 (MODE1: v1; MODE2: v1+v2), overlaps DMA ----
  h2f vh[Cn][2];
  if (MODE >= 1) {
    const float4* spA = reinterpret_cast<const float4*>(s1 + (size_t)b * ROW);
    const float4* spB = reinterpret_cast<const float4*>(s2 + (size_t)b * ROW);
#pragma unroll
    for (int c = 0; c < Cn; ++c) {
      const float4 a0 = spA[c * 4 + 0], a1 = spA[c * 4 + 1];
      const float4 a2 = spA[c * 4 + 2], a3 = spA[c * 4 + 3];
      float sqA = a0.x * a0.x + a0.y * a0.y + a0.z * a0.z + a0.w * a0.w;
      sqA += a1.x * a1.x + a1.y * a1.y + a1.z * a1.z + a1.w * a1.w;
      sqA += a2.x * a2.x + a2.y * a2.y + a2.z * a2.z + a2.w * a2.w;
      sqA += a3.x * a3.x + a3.y * a3.y + a3.z * a3.z + a3.w * a3.w;
      sqA *= 0.01f; // v1 scale is always 0.1
      const float facA = 0.1f * (sqA / (1.f + sqA)) / sqrtf(sqA + 1e-9f);
      const float4 qa = spA[c * 4 + quad]; // L1 re-hit
      float v0 = facA * qa.x, v1_ = facA * qa.y;
      float v2_ = facA * qa.z, v3_ = facA * qa.w;
      if (MODE == 2) { // add v2 = squash(s2)
        const float4 b0 = spB[c * 4 + 0], b1 = spB[c * 4 + 1];
        const float4 b2 = spB[c * 4 + 2], b3 = spB[c * 4 + 3];
        float sqB = b0.x * b0.x + b0.y * b0.y + b0.z * b0.z + b0.w * b0.w;
        sqB += b1.x * b1.x + b1.y * b1.y + b1.z * b1.z + b1.w * b1.w;
        sqB += b2.x * b2.x + b2.y * b2.y + b2.z * b2.z + b2.w * b2.w;
        sqB += b3.x * b3.x + b3.y * b3.y + b3.z * b3.z + b3.w * b3.w;
        const float facB = (sqB / (1.f + sqB)) / sqrtf(sqB + 1e-9f);
        const float4 qb = spB[c * 4 + quad];
        v0 += facB * qb.x; v1_ += facB * qb.y;
        v2_ += facB * qb.z; v3_ += facB * qb.w;
      }
      vh[c][0] = pack2(v0, v1_);
      vh[c][1] = pack2(v2_, v3_);
    }
  }

  f32x4 acc[Cn];
  const f32x4 zc = {0.f, 0.f, 0.f, 0.f};
#pragma unroll
  for (int c = 0; c < Cn; ++c) acc[c] = zc;

  const _Float16* urow = uT + ((size_t)p0 * Bn + b) * In;
  f16x8 ufA = *reinterpret_cast<const f16x8*>(urow);
  f16x8 ufB = *reinterpret_cast<const f16x8*>(urow + (size_t)Bn * In);
  const f16x8 zb = {0, 0, 0, 0, 0, 0, 0, 0};
  const bool isq0 = (quad == 0);

  __syncthreads(); // drains DMA -> wH ready (the ONLY barrier)

  for (int ip = 0; ip < PPB; ip += 2) { // 2 p's per iter: independent chains
    f16x8 nfA = ufA, nfB = ufB;
    if (ip + 2 < PPB) { // u prefetch (named regs); 256B/wave contiguous
      nfA = *reinterpret_cast<const f16x8*>(urow + (size_t)(ip + 2) * Bn * In);
      nfB = *reinterpret_cast<const f16x8*>(urow + (size_t)(ip + 3) * Bn * In);
    }
    const f16x8 ubA = isq0 ? ufA : zb; // quads 1-3: K-pad zeros
    const f16x8 ubB = isq0 ? ufB : zb;
    const _Float16* wpA = wH + (size_t)ip * 1280 + col * 8; // A: W[p][c][col]
    const _Float16* wpB = wpA + 1280;

    if (MODE == 0) {
#pragma unroll
      for (int c = 0; c < Cn; ++c) {
        const f16x8 aWA = *reinterpret_cast<const f16x8*>(wpA + c * 128);
        const f16x8 aWB = *reinterpret_cast<const f16x8*>(wpB + c * 128);
        acc[c] = __builtin_amdgcn_mfma_f32_16x16x32_f16(aWA, ubA, acc[c], 0, 0, 0);
        acc[c] = __builtin_amdgcn_mfma_f32_16x16x32_f16(aWB, ubB, acc[c], 0, 0, 0);
      }
    } else {
      float lfA[Cn], lfB[Cn];
      h2f uhA[Cn][2], uhB[Cn][2];
#pragma unroll
      for (int c = 0; c < Cn; ++c) {
        const f16x8 aWA = *reinterpret_cast<const f16x8*>(wpA + c * 128);
        const f16x8 aWB = *reinterpret_cast<const f16x8*>(wpB + c * 128);
        const f32x4 dA =
            __builtin_amdgcn_mfma_f32_16x16x32_f16(aWA, ubA, zc, 0, 0, 0);
        const f32x4 dB =
            __builtin_amdgcn_mfma_f32_16x16x32_f16(aWB, ubB, zc, 0, 0, 0);
        float la = dA[0] * (float)vh[c][0][0];
        la = __builtin_fmaf(dA[1], (float)vh[c][0][1], la);
        la = __builtin_fmaf(dA[2], (float)vh[c][1][0], la);
        la = __builtin_fmaf(dA[3], (float)vh[c][1][1], la);
        lfA[c] = la;
        float lb = dB[0] * (float)vh[c][0][0];
        lb = __builtin_fmaf(dB[1], (float)vh[c][0][1], lb);
        lb = __builtin_fmaf(dB[2], (float)vh[c][1][0], lb);
        lb = __builtin_fmaf(dB[3], (float)vh[c][1][1], lb);
        lfB[c] = lb;
        uhA[c][0] = pack2(dA[0], dA[1]);
        uhA[c][1] = pack2(dA[2], dA[3]);
        uhB[c][0] = pack2(dB[0], dB[1]);
        uhB[c][1] = pack2(dB[2], dB[3]);
      }
      // quad reduce: 2 shuffles per c, A/B interleaved (independent)
#pragma unroll
      for (int c = 0; c < Cn; ++c) {
        lfA[c] += __shfl_xor(lfA[c], 16, 64);
        lfB[c] += __shfl_xor(lfB[c], 16, 64);
        lfA[c] += __shfl_xor(lfA[c], 32, 64);
        lfB[c] += __shfl_xor(lfB[c], 32, 64);
      }
      // softmax over 10 in-lane, A and B chains independent
      float mA = fmaxf(fmaxf(lfA[0], lfA[1]), fmaxf(lfA[2], lfA[3]));
      float mB = fmaxf(fmaxf(lfB[0], lfB[1]), fmaxf(lfB[2], lfB[3]));
      mA = fmaxf(mA, fmaxf(fmaxf(lfA[4], lfA[5]), fmaxf(lfA[6], lfA[7])));
      mB = fmaxf(mB, fmaxf(fmaxf(lfB[4], lfB[5]), fmaxf(lfB[6], lfB[7])));
      mA = fmaxf(mA, fmaxf(lfA[8], lfA[9]));
      mB = fmaxf(mB, fmaxf(lfB[8], lfB[9]));
      float ssA = 0.f, ssB = 0.f;
#pragma unroll
      for (int c = 0; c < Cn; ++c) {
        lfA[c] = __expf(lfA[c] - mA);
        ssA += lfA[c];
        lfB[c] = __expf(lfB[c] - mB);
        ssB += lfB[c];
      }
      const float invA = 1.f / ssA;
      const float invB = 1.f / ssB;
#pragma unroll
      for (int c = 0; c < Cn; ++c) {
        const float cvA = lfA[c] * invA;
        const float cvB = lfB[c] * invB;
        float t0 = __builtin_fmaf(cvA, (float)uhA[c][0][0], acc[c][0]);
        float t1 = __builtin_fmaf(cvA, (float)uhA[c][0][1], acc[c][1]);
        float t2 = __builtin_fmaf(cvA, (float)uhA[c][1][0], acc[c][2]);
        float t3 = __builtin_fmaf(cvA, (float)uhA[c][1][1], acc[c][3]);
        acc[c][0] = __builtin_fmaf(cvB, (float)uhB[c][0][0], t0);
        acc[c][1] = __builtin_fmaf(cvB, (float)uhB[c][0][1], t1);
        acc[c][2] = __builtin_fmaf(cvB, (float)uhB[c][1][0], t2);
        acc[c][3] = __builtin_fmaf(cvB, (float)uhB[c][1][1], t3);
      }
    }
    ufA = nfA;
    ufB = nfB;
  }

  // ---- partial store: owner-unique, full-line coalesced, NO atomics ----
  float* pb = part + ((size_t)x * BT + w * 16 + col) * ROW;
#pragma unroll
  for (int c = 0; c < Cn; ++c)
    *reinterpret_cast<f32x4*>(pb + c * 16 + quad * 4) = acc[c];
}

// ---- sum partials -> s. grid (160,4): chunk = 32 p-tiles, atomicAdd (s
// memset once, 4 contenders/cell). Coalesced reads per wave.
__global__ __launch_bounds__(256) void k_red(const float* __restrict__ part,
                                             float* __restrict__ s) {
  const int cell = blockIdx.x * 256 + threadIdx.x; // [0, 40960)
  const int chunk = blockIdx.y;                    // 0..3
  const int b = cell / 160, rem = cell - 160 * b;
  const int bt = b >> 6, bl = b & 63;
  const float* p0 =
      part + ((size_t)(bt * NPT + chunk * 32) * BT + bl) * ROW + rem;
  float a0 = 0.f, a1 = 0.f, a2 = 0.f, a3 = 0.f;
  float a4 = 0.f, a5 = 0.f, a6 = 0.f, a7 = 0.f;
#pragma unroll
  for (int pt = 0; pt < 32; pt += 8) { // 8 independent load chains
    a0 += p0[(size_t)(pt + 0) * BT * ROW];
    a1 += p0[(size_t)(pt + 1) * BT * ROW];
    a2 += p0[(size_t)(pt + 2) * BT * ROW];
    a3 += p0[(size_t)(pt + 3) * BT * ROW];
    a4 += p0[(size_t)(pt + 4) * BT * ROW];
    a5 += p0[(size_t)(pt + 5) * BT * ROW];
    a6 += p0[(size_t)(pt + 6) * BT * ROW];
    a7 += p0[(size_t)(pt + 7) * BT * ROW];
  }
  atomicAdd(&s[cell], ((a0 + a1) + (a2 + a3)) + ((a4 + a5) + (a6 + a7)));
}

__global__ __launch_bounds__(256) void k_out(const float* __restrict__ s,
                                             float* __restrict__ out) {
  const int gi = blockIdx.x * 256 + threadIdx.x; // [0, 2560) = (b,c)
  const int b = gi / 10, c = gi - 10 * b;
  const float* sp = s + (size_t)b * ROW + c * 16;
  float sq = 0.f;
#pragma unroll
  for (int o = 0; o < On; ++o) { const float xx = sp[o]; sq += xx * xx; }
  const float fac = (sq / (1.f + sq)) / sqrtf(sq + 1e-9f);
  float* op = out + (size_t)b * ROW + c * 16;
#pragma unroll
  for (int o = 0; o < On; ++o) op[o] = fac * sp[o];
}

extern "C" void kernel_launch(void* const* d_in, const int* in_sizes, int n_in,
                              void* d_out, int out_size, void* d_ws, size_t ws_size,
                              hipStream_t stream) {
  (void)in_sizes; (void)n_in; (void)out_size;
  const float* u = (const float*)d_in[0];
  const float* W = (const float*)d_in[1];
  float* out = (float*)d_out;
  float* s1 = (float*)d_ws;                    // 3 x [256][160] fp32
  float* s2 = s1 + (size_t)Bn * ROW;
  float* s3 = s2 + (size_t)Bn * ROW;
  float* part = s3 + (size_t)Bn * ROW;         // [512][64][160] fp32, 21MB
  _Float16* Wh = (_Float16*)(part + (size_t)GRID * BT * ROW); // 5.25MB
  _Float16* uTp = Wh + (size_t)Pn * Cn * On * In;             // 8.4MB
  const size_t need =
      ((size_t)3 * Bn * ROW + (size_t)GRID * BT * ROW) * sizeof(float) +
      ((size_t)Pn * Cn * On * In + (size_t)Pn * Bn * In) * sizeof(_Float16);
  if (ws_size < need) return;
  hipMemsetAsync(s1, 0, (size_t)3 * Bn * ROW * sizeof(float), stream);
  k_prepw<<<Pn, 256, 0, stream>>>(W, Wh);
  k_prepu<<<Pn / 2, 256, 0, stream>>>(u, uTp);
  k_cap<0><<<GRID, TPB, 0, stream>>>(uTp, Wh, s1, s1, part);
  k_red<<<dim3(160, 4), 256, 0, stream>>>(part, s1);
  k_cap<1><<<GRID, TPB, 0, stream>>>(uTp, Wh, s1, s1, part);
  k_red<<<dim3(160, 4), 256, 0, stream>>>(part, s2);
  k_cap<2><<<GRID, TPB, 0, stream>>>(uTp, Wh, s1, s2, part);
  k_red<<<dim3(160, 4), 256, 0, stream>>>(part, s3);
  k_out<<<10, 256, 0, stream>>>(s3, out);
}